// Round 1
// baseline (119.864 us; speedup 1.0000x reference)
//
#include <hip/hip_runtime.h>
#include <hip/hip_bf16.h>

// DecorrelationGradient, KAPPA = 0.5:
//   out = 0.5 * (X^T X / N) - 0.5   (diag terms cancel exactly at k=0.5)
// X [16384, 768] fp32.
//
// R3: atomic epilogue was the wall -> bf16 partials + reduce (no atomics).
// R4 (this round):
//   - K3: 2-phase double-buffered prefetch (guide T3 minimum template):
//     STAGE(next buf) issued BEFORE ds_read+MFMA(cur), ONE barrier/K-step.
//     Old structure exposed full LLC latency behind a vmcnt(0) drain twice
//     per K-step with only ~2.6 blocks/CU of TLP to hide it.
//   - K3: diagonal pairs (mi==ni) skip B staging, read B-frags from ldsA.
//   - K4: short8-vectorized partial loads (was scalar u16), float4 stores,
//     mirror via LDS transpose (was stride-3072B scalar scatter).

#define D_DIM    768
#define K_DIM    16384
#define NPAIR    21
#define KSPLIT   32
#define KCHUNK   (K_DIM / KSPLIT)       // 512 -> 16 iters of BK=32
#define XT_BYTES ((size_t)D_DIM * K_DIM * 2)                  // 24 MiB
#define PART_BYTES ((size_t)KSPLIT * NPAIR * 16384 * 2)       // 21 MiB

__device__ __constant__ int MI_TAB[NPAIR] = {0,0,0,0,0,0, 1,1,1,1,1, 2,2,2,2, 3,3,3, 4,4, 5};
__device__ __constant__ int NI_TAB[NPAIR] = {0,1,2,3,4,5, 1,2,3,4,5, 2,3,4,5, 3,4,5, 4,5, 5};

typedef __attribute__((ext_vector_type(8))) short short8;     // bf16 A/B frag
typedef __attribute__((ext_vector_type(4))) float floatx4;    // fp32 C/D frag

typedef __attribute__((address_space(3))) unsigned short lds_ushort;
typedef __attribute__((address_space(1))) const unsigned short g_ushort;

__device__ __forceinline__ void load_lds16(const unsigned short* g, unsigned short* l) {
  __builtin_amdgcn_global_load_lds((g_ushort*)g, (lds_ushort*)l, 16, 0, 0);
}

__device__ __forceinline__ unsigned short f2bf(float f) {
  unsigned int u = __float_as_uint(f);
  u += 0x7fffu + ((u >> 16) & 1u);
  return (unsigned short)(u >> 16);
}
__device__ __forceinline__ float bf2f(unsigned short u) {
  return __uint_as_float((unsigned int)u << 16);
}

// ---------------- K1: transpose + cast -------------------------------------
__global__ __launch_bounds__(256) void transpose_cast_kernel(
    const float* __restrict__ x, unsigned short* __restrict__ xt) {
  __shared__ __align__(16) unsigned short tile[64 * 66];
  const int d0 = blockIdx.x * 64;
  const int n0 = blockIdx.y * 64;
  const int t  = threadIdx.x;
  const int c4 = t & 15;
  const int r  = t >> 4;
#pragma unroll
  for (int i = 0; i < 4; ++i) {
    const int n = r + 16 * i;
    float4 v = *(const float4*)(x + (size_t)(n0 + n) * D_DIM + d0 + c4 * 4);
    ushort2 lo, hi;
    lo.x = f2bf(v.x); lo.y = f2bf(v.y);
    hi.x = f2bf(v.z); hi.y = f2bf(v.w);
    *(ushort2*)&tile[n * 66 + c4 * 4]     = lo;
    *(ushort2*)&tile[n * 66 + c4 * 4 + 2] = hi;
  }
  __syncthreads();
  const int ck = t & 7;
  const int rr = t >> 3;
#pragma unroll
  for (int i = 0; i < 2; ++i) {
    const int d = rr + 32 * i;
    unsigned int w[4];
#pragma unroll
    for (int j = 0; j < 4; ++j) {
      unsigned int a = tile[(ck * 8 + 2 * j)     * 66 + d];
      unsigned int b = tile[(ck * 8 + 2 * j + 1) * 66 + d];
      w[j] = a | (b << 16);
    }
    uint4 o; o.x = w[0]; o.y = w[1]; o.z = w[2]; o.w = w[3];
    *(uint4*)(xt + (size_t)(d0 + d) * K_DIM + n0 + ck * 8) = o;
  }
}

// ---------------- K3: Gram GEMM, 2-phase double-buffered -------------------
template<int KS, bool ATOMIC>
__global__ __launch_bounds__(256, 4) void gram_gemm_kernel(
    const unsigned short* __restrict__ xt,
    unsigned short* __restrict__ partials,   // bf16 [KS][NPAIR][16384]
    float* __restrict__ out) {
  __shared__ __align__(16) unsigned short ldsA[2][128 * 32];
  __shared__ __align__(16) unsigned short ldsB[2][128 * 32];

  const int p  = blockIdx.x;
  const int mi = MI_TAB[p];
  const int ni = NI_TAB[p];
  const bool offdiag = (mi != ni);
  const int m0 = mi * 128;
  const int n0 = ni * 128;
  const int kz = blockIdx.y;

  const int t    = threadIdx.x;
  const int wave = t >> 6;
  const int lane = t & 63;
  const int wm   = (wave >> 1) * 64;
  const int wn   = (wave & 1) * 64;
  const int lm   = lane & 15;
  const int quad = lane >> 4;

  floatx4 zero = {0.f, 0.f, 0.f, 0.f};
  floatx4 acc[4][4];
#pragma unroll
  for (int a = 0; a < 4; ++a)
#pragma unroll
    for (int b = 0; b < 4; ++b) acc[a][b] = zero;

  const int kbeg = kz * (K_DIM / KS);
  constexpr int NIT = (K_DIM / KS) / 32;

  // precomputed staging addresses (i = 0,1 -> two 1KB wave-chunks each)
  const unsigned short* gA[2];
  const unsigned short* gB[2];
  unsigned int lofs[2];
#pragma unroll
  for (int i = 0; i < 2; ++i) {
    const int flatL = (wave * 2 + i) * 64 + lane;
    const int rrow  = flatL >> 2;
    const int sub   = flatL & 3;
    gA[i] = xt + (size_t)(m0 + rrow) * K_DIM + kbeg + sub * 8;
    gB[i] = xt + (size_t)(n0 + rrow) * K_DIM + kbeg + sub * 8;
    lofs[i] = (unsigned int)flatL * 8;
  }

  auto STAGE = [&](int buf, int koff) {
#pragma unroll
    for (int i = 0; i < 2; ++i) {
      load_lds16(gA[i] + koff, &ldsA[buf][lofs[i]]);
      if (offdiag) load_lds16(gB[i] + koff, &ldsB[buf][lofs[i]]);
    }
  };

  auto COMPUTE = [&](int buf) {
    const unsigned short* aB = &ldsA[buf][0];
    const unsigned short* bB = offdiag ? &ldsB[buf][0] : &ldsA[buf][0];
    short8 af[4], bfr[4];
#pragma unroll
    for (int a = 0; a < 4; ++a)
      af[a] = *(const short8*)&aB[(wm + a * 16 + lm) * 32 + quad * 8];
#pragma unroll
    for (int b = 0; b < 4; ++b)
      bfr[b] = *(const short8*)&bB[(wn + b * 16 + lm) * 32 + quad * 8];
#pragma unroll
    for (int a = 0; a < 4; ++a)
#pragma unroll
      for (int b = 0; b < 4; ++b)
        acc[a][b] = __builtin_amdgcn_mfma_f32_16x16x32_bf16(
            af[a], bfr[b], acc[a][b], 0, 0, 0);
  };

  // prologue: stage tile 0, drain, barrier
  STAGE(0, 0);
  __syncthreads();   // compiler emits vmcnt(0) drain before s_barrier

  int cur = 0;
  for (int it = 0; it < NIT - 1; ++it) {
    STAGE(cur ^ 1, (it + 1) * 32);   // issue next-tile loads FIRST
    COMPUTE(cur);                    // ds_read + MFMA overlap the loads
    __syncthreads();                 // one barrier per K-step (drains vmcnt)
    cur ^= 1;
  }
  COMPUTE(cur);                      // epilogue tile, no prefetch

  if (ATOMIC) {
    const float scale = 0.5f / (float)K_DIM;
#pragma unroll
    for (int a = 0; a < 4; ++a)
#pragma unroll
      for (int b = 0; b < 4; ++b)
#pragma unroll
        for (int r2 = 0; r2 < 4; ++r2) {
          const int grow = m0 + wm + a * 16 + quad * 4 + r2;
          const int gcol = n0 + wn + b * 16 + lm;
          atomicAdd(&out[(size_t)grow * D_DIM + gcol], acc[a][b][r2] * scale);
        }
  } else {
    // store raw bf16 partial, local row-major 128x128
    unsigned short* pb = partials + ((size_t)kz * NPAIR + p) * 16384;
#pragma unroll
    for (int a = 0; a < 4; ++a)
#pragma unroll
      for (int b = 0; b < 4; ++b)
#pragma unroll
        for (int r2 = 0; r2 < 4; ++r2) {
          const int lr = wm + a * 16 + quad * 4 + r2;
          const int lc = wn + b * 16 + lm;
          pb[lr * 128 + lc] = f2bf(acc[a][b][r2]);
        }
  }
}

// ---------------- K4: reduce + affine + mirror (vectorized) ----------------
// grid: 21*16384/(256*8) = 168 blocks. Each block: one 16-row x 128-col strip
// of one tile-pair. Thread handles 8 contiguous elems (one short8 per kz).
__global__ __launch_bounds__(256) void reduce_kernel(
    const unsigned short* __restrict__ partials, float* __restrict__ out) {
  __shared__ float sm[128][17];       // transposed strip for mirror writes

  const int tid = threadIdx.x;
  const int tpi = blockIdx.x >> 3;          // tile-pair index (8 blocks/pair)
  const int r0b = (blockIdx.x & 7) * 16;    // row base of this strip
  const int rl  = tid >> 4;                 // 0..15 row within strip
  const int c0  = (tid & 15) * 8;           // 0..120 col base (8 elems)
  const int r   = r0b + rl;
  const int e8  = r * 128 + c0;

  const unsigned short* pb = partials + (size_t)tpi * 16384 + e8;
  float v[8];
#pragma unroll
  for (int j = 0; j < 8; ++j) v[j] = 0.f;
  for (int kz = 0; kz < KSPLIT; ++kz) {
    short8 w = *(const short8*)(pb + (size_t)kz * (NPAIR * 16384));
#pragma unroll
    for (int j = 0; j < 8; ++j) v[j] += bf2f((unsigned short)w[j]);
  }
  const float scale = 0.5f / (float)K_DIM;
#pragma unroll
  for (int j = 0; j < 8; ++j) v[j] = v[j] * scale - 0.5f;

  const int mi = MI_TAB[tpi], ni = NI_TAB[tpi];
  const int m0 = mi * 128, n0 = ni * 128;

  // direct write: coalesced float4 x2
  float4 o0 = make_float4(v[0], v[1], v[2], v[3]);
  float4 o1 = make_float4(v[4], v[5], v[6], v[7]);
  float* dst = out + (size_t)(m0 + r) * D_DIM + n0 + c0;
  *(float4*)dst       = o0;
  *(float4*)(dst + 4) = o1;

  if (mi != ni) {
    // mirror via LDS transpose: strip [16 r][128 c] -> [128 c][16 r]
#pragma unroll
    for (int j = 0; j < 8; ++j) sm[c0 + j][rl] = v[j];
    __syncthreads();
    const int row2 = tid >> 1;          // 0..127: col of direct tile
    const int h8   = (tid & 1) * 8;     // which 8 of the 16 strip-rows
    float4 m0v = make_float4(sm[row2][h8 + 0], sm[row2][h8 + 1],
                             sm[row2][h8 + 2], sm[row2][h8 + 3]);
    float4 m1v = make_float4(sm[row2][h8 + 4], sm[row2][h8 + 5],
                             sm[row2][h8 + 6], sm[row2][h8 + 7]);
    float* mdst = out + (size_t)(n0 + row2) * D_DIM + m0 + r0b + h8;
    *(float4*)mdst       = m0v;
    *(float4*)(mdst + 4) = m1v;
  }
}

// ---------------- fallback init (atomic path only) -------------------------
__global__ __launch_bounds__(256) void init_out_kernel(float* __restrict__ out) {
  size_t i = (size_t)blockIdx.x * 256 + threadIdx.x;
  ((float4*)out)[i] = make_float4(-0.5f, -0.5f, -0.5f, -0.5f);
}
__global__ __launch_bounds__(256) void mirror_kernel(float* __restrict__ out) {
  const int idx = blockIdx.x * 256 + threadIdx.x;
  const int r = idx / D_DIM;
  const int c = idx - r * D_DIM;
  if ((r >> 7) > (c >> 7))
    out[idx] = out[(size_t)c * D_DIM + r];
}

extern "C" void kernel_launch(void* const* d_in, const int* in_sizes, int n_in,
                              void* d_out, int out_size, void* d_ws, size_t ws_size,
                              hipStream_t stream) {
  const float* x = (const float*)d_in[0];           // [16384,768] f32
  float* out = (float*)d_out;                       // [768,768] f32
  unsigned short* xt = (unsigned short*)d_ws;       // bf16 [768][16384]

  transpose_cast_kernel<<<dim3(12, 256), 256, 0, stream>>>(x, xt);

  if (ws_size >= XT_BYTES + PART_BYTES) {
    unsigned short* parts = (unsigned short*)((char*)d_ws + XT_BYTES);
    gram_gemm_kernel<KSPLIT, false><<<dim3(NPAIR, KSPLIT), 256, 0, stream>>>(xt, parts, out);
    reduce_kernel<<<NPAIR * 16384 / (256 * 8), 256, 0, stream>>>(parts, out);
  } else {
    // atomic fallback (slower, small ws): KSPLIT=8 to limit RMW contention
    init_out_kernel<<<576, 256, 0, stream>>>(out);
    gram_gemm_kernel<8, true><<<dim3(NPAIR, 8), 256, 0, stream>>>(xt, nullptr, out);
    mirror_kernel<<<2304, 256, 0, stream>>>(out);
  }
}